// Round 26
// baseline (448.543 us; speedup 1.0000x reference)
//
#include <hip/hip_runtime.h>

typedef _Float16 f16;
typedef _Float16 f16x4_t __attribute__((ext_vector_type(4)));
typedef _Float16 f16x8_t __attribute__((ext_vector_type(8)));
typedef float    f32x4_t  __attribute__((ext_vector_type(4)));
typedef float    f32x16_t __attribute__((ext_vector_type(16)));

#define HD 512          // h
#define CD 256          // c
#define ND 512          // N (codebook)
#define MROWS (4*24*2048)
#define BM 32           // 32 rows/WG -> LDS ~34KB -> 4 WGs/CU (wave cap)
#define NTHR 512
#define TINV 10.0f      // 1/TEMP

// C/D layout of mfma_f32_32x32x16 (HW-measured, dtype-independent):
// col = lane&31, row = (reg&3) + 8*(reg>>2) + 4*(lane>>5), reg in [0,16)
__device__ __forceinline__ int crow(int r, int hi) {
  return (r & 3) + 8 * (r >> 2) + 4 * hi;
}

// B-fragment address (f16 units) for 32x32x16: frag=(col>>5)*ktiles + (k>>4),
// lane=((k>>3)&1)*32 + (col&31), j=k&7
__device__ __forceinline__ int fragoff32(int col, int k, int ktiles) {
  return (((col >> 5) * ktiles + (k >> 4)) * 64 + ((k >> 3) & 1) * 32 + (col & 31)) * 8 + (k & 7);
}

// ---------------- prep: M = Wp @ Wq -> fp16 32x32-fragments (unscaled); sb[n] = dot(Wp[n], bq)
__global__ void prep_M(const float* __restrict__ Wp, const float* __restrict__ Wq,
                       const float* __restrict__ bq, f16* __restrict__ MtF,
                       float* __restrict__ sb) {
  const int n = blockIdx.x;   // 0..511
  const int t = threadIdx.x;  // 0..255
  __shared__ float wpr[CD];
  __shared__ float sred[CD];
  wpr[t] = Wp[n * CD + t];
  __syncthreads();
  float a0 = 0.f, a1 = 0.f;
  #pragma unroll 8
  for (int c = 0; c < CD; ++c) {
    const float w = wpr[c];
    a0 = fmaf(w, Wq[c * HD + t], a0);
    a1 = fmaf(w, Wq[c * HD + t + 256], a1);
  }
  MtF[fragoff32(n, t, 32)]       = (f16)a0;
  MtF[fragoff32(n, t + 256, 32)] = (f16)a1;
  sred[t] = wpr[t] * bq[t];
  __syncthreads();
  for (int s = 128; s > 0; s >>= 1) {
    if (t < s) sred[t] += sred[t + s];
    __syncthreads();
  }
  if (t == 0) sb[n] = sred[0];
}

// ---------------- prep: WpF = GEMM3 B 32x32-fragments (k = n in 512, cols = c in 256)
__global__ void prep_WpF(const float* __restrict__ Wp, f16* __restrict__ WpF) {
  const int bx   = blockIdx.x;        // frag idx = (c>>5)*32 + (n>>4), 0..255
  const int lane = threadIdx.x;       // 0..63
  const int cf = bx >> 5, kt = bx & 31;
  const int hi = lane >> 5, c32 = lane & 31;
  f16x8_t v;
  #pragma unroll
  for (int j = 0; j < 8; ++j) {
    const int n = kt * 16 + hi * 8 + j;
    v[j] = (f16)Wp[n * CD + cf * 32 + c32];
  }
  *(f16x8_t*)(WpF + ((bx * 64) + lane) * 8) = v;
}

// ---------------- fused main: R24 config (BM=32, NT, 4 WGs/CU, 4 barriers) with
// 32x32x16 MFMA (R26). Why: 32x32 C-layout puts 32 lanes on ONE row per store
// instruction -> every Q/P NT store covers full 128B lines, fixing the 64B
// scatter granule responsible for the ~300-400MB write inflation. R17 tested
// this shape confounded (allocating stores, BM=64, TINV-folding) -- all now fixed.
// Falsifier: dur >= 335 or FETCH >= 450MB -> restore R24, declare floor.
// Register model: (512,4) -> 128 total regs/wave; acc 32 AGPR + acc2 16 AGPR.
// SWIZZLE RULE (R4): XOR the FULL byte offset (XOR-last); mask (row&31)<<4.
__global__ __launch_bounds__(NTHR, 4)
void fused_main(const float* __restrict__ Hl, const f16* __restrict__ MtF,
                const f16* __restrict__ WpF, const float* __restrict__ sb,
                float* __restrict__ outP, float* __restrict__ outQ) {
  __shared__ __align__(16) char AQraw[BM * HD * 2];   // 32 KiB: H fp16 -> Q fp16
  __shared__ float red[BM][8];
  __shared__ float rstat[BM];

  const int tid  = threadIdx.x;
  const int lane = tid & 63;
  const int wid  = tid >> 6;         // 0..7
  const int l31  = lane & 31;
  const int hi   = lane >> 5;        // 0..1
  const long rowbase = (long)blockIdx.x * BM;

  // ---- stage H: 32 rows x 512 fp32 -> fp16 LDS (swizzled); NT loads ----
  {
    const f32x4_t* __restrict__ src = (const f32x4_t*)(Hl + rowbase * HD);
    #pragma unroll
    for (int it = 0; it < (BM * HD / 4) / NTHR; ++it) {   // 8 iters
      const int f = it * NTHR + tid;
      const f32x4_t v = __builtin_nontemporal_load(&src[f]);
      const int row = f >> 7;
      int byteoff = row * (HD * 2) + ((f & 127) << 3);
      byteoff ^= (row & 31) << 4;                    // XOR-last!
      f16x4_t h;
      h[0] = (f16)v[0]; h[1] = (f16)v[1]; h[2] = (f16)v[2]; h[3] = (f16)v[3];
      *(f16x4_t*)(AQraw + byteoff) = h;
    }
  }
  __syncthreads();                                   // barrier 1

  // ---- GEMM1: wave tile 32 rows x 64 cols as 1x2 of 32x32 frags ----
  f32x16_t acc[2];
  #pragma unroll
  for (int j = 0; j < 2; ++j)
    #pragma unroll
    for (int k = 0; k < 16; ++k) acc[j][k] = 0.f;

  {
    const char* __restrict__ mb = (const char*)MtF + wid * (2 * 32 * 1024) + lane * 16;
    for (int kt = 0; kt < 32; ++kt) {                // K = 512 / 16
      int byteoff = l31 * (HD * 2) + kt * 32 + hi * 16;
      byteoff ^= (l31 & 31) << 4;                    // XOR-last!
      const f16x8_t a = *(const f16x8_t*)(AQraw + byteoff);
      #pragma unroll
      for (int nf = 0; nf < 2; ++nf) {
        const f16x8_t b = *(const f16x8_t*)(mb + (nf * 32 + kt) * 1024);
        acc[nf] = __builtin_amdgcn_mfma_f32_32x32x16_f16(a, b, acc[nf], 0, 0, 0);
      }
    }
  }

  // ---- softmax over N=512, direct exp (|logit| <~ 54 << 88) ----
  // thread holds rows crow(r,hi), cols wid*64 + nf*32 + l31
  float sb10[2];
  #pragma unroll
  for (int nf = 0; nf < 2; ++nf) sb10[nf] = sb[wid * 64 + nf * 32 + l31] * TINV;

  float ps[16];
  #pragma unroll
  for (int r = 0; r < 16; ++r) ps[r] = 0.f;
  #pragma unroll
  for (int nf = 0; nf < 2; ++nf)
    #pragma unroll
    for (int r = 0; r < 16; ++r) {
      const float e = __expf(fmaf(acc[nf][r], TINV, sb10[nf]));
      acc[nf][r] = e;
      ps[r] += e;
    }
  #pragma unroll
  for (int st = 16; st >= 1; st >>= 1)               // reduce over 32 col-lanes
    #pragma unroll
    for (int r = 0; r < 16; ++r)
      ps[r] += __shfl_xor(ps[r], st, 64);

  if (l31 == 0) {                                    // lanes 0 and 32 (hi disjoint rows)
    #pragma unroll
    for (int r = 0; r < 16; ++r)
      red[crow(r, hi)][wid] = ps[r];
  }
  __syncthreads();                                   // barrier 2
  if (tid < BM) {
    const float* rr = red[tid];
    rstat[tid] = 1.0f / (rr[0] + rr[1] + rr[2] + rr[3] + rr[4] + rr[5] + rr[6] + rr[7]);
  }
  __syncthreads();                                   // barrier 3

  // ---- normalize: Q fp32 NT stores (2 full 128B lines/instr) + Q fp16 into LDS ----
  {
    float rv[16];
    #pragma unroll
    for (int r = 0; r < 16; ++r)
      rv[r] = rstat[crow(r, hi)];
    #pragma unroll
    for (int nf = 0; nf < 2; ++nf)
      #pragma unroll
      for (int r = 0; r < 16; ++r) {
        const int rloc = crow(r, hi);
        const int col  = wid * 64 + nf * 32 + l31;
        const float q = acc[nf][r] * rv[r];
        __builtin_nontemporal_store(q, &outQ[(rowbase + rloc) * ND + col]);
        int byteoff = rloc * (ND * 2) + col * 2;
        byteoff ^= (rloc & 31) << 4;                 // XOR-last!
        *(f16*)(AQraw + byteoff) = (f16)q;
      }
  }
  __syncthreads();                                   // barrier 4: Q-LDS ready

  // ---- GEMM3: wave tile 32 rows x 32 cols (one 32x32 frag); K = n = 512 ----
  f32x16_t acc2;
  #pragma unroll
  for (int k = 0; k < 16; ++k) acc2[k] = 0.f;

  {
    const char* __restrict__ wb = (const char*)WpF + wid * (32 * 1024) + lane * 16;
    for (int kt = 0; kt < 32; ++kt) {
      int byteoff = l31 * (ND * 2) + kt * 32 + hi * 16;
      byteoff ^= (l31 & 31) << 4;                    // XOR-last!
      const f16x8_t a = *(const f16x8_t*)(AQraw + byteoff);
      const f16x8_t b = *(const f16x8_t*)(wb + kt * 1024);
      acc2 = __builtin_amdgcn_mfma_f32_32x32x16_f16(a, b, acc2, 0, 0, 0);
    }
  }

  // ---- P fp32 NT stores (2 full 128B lines/instr) ----
  #pragma unroll
  for (int r = 0; r < 16; ++r) {
    const long row = rowbase + crow(r, hi);
    const int  col = wid * 32 + l31;
    __builtin_nontemporal_store(acc2[r], &outP[row * CD + col]);
  }
}

extern "C" void kernel_launch(void* const* d_in, const int* in_sizes, int n_in,
                              void* d_out, int out_size, void* d_ws, size_t ws_size,
                              hipStream_t stream) {
  const float* Hl = (const float*)d_in[0];   // (B,T,V,H)
  const float* Wp = (const float*)d_in[1];   // (N,C)
  const float* Wq = (const float*)d_in[2];   // (C,H)
  const float* bq = (const float*)d_in[3];   // (C,)

  float* outP = (float*)d_out;                         // (M, C)
  float* outQ = (float*)d_out + (long)MROWS * CD;      // (M, N)

  f16*   MtF = (f16*)d_ws;                                        // 512 KiB
  f16*   WpF = (f16*)((char*)d_ws + ND * HD * 2);                 // 256 KiB
  float* sb  = (float*)((char*)d_ws + ND * HD * 2 + CD * ND * 2); // 2 KiB

  prep_M  <<<ND, CD, 0, stream>>>(Wp, Wq, bq, MtF, sb);
  prep_WpF<<<CD, 64, 0, stream>>>(Wp, WpF);
  fused_main<<<MROWS / BM, NTHR, 0, stream>>>(Hl, MtF, WpF, sb, outP, outQ);
}

// Round 27
// 330.607 us; speedup vs baseline: 1.3567x; 1.3567x over previous
//
#include <hip/hip_runtime.h>

typedef _Float16 f16;
typedef _Float16 f16x4_t __attribute__((ext_vector_type(4)));
typedef _Float16 f16x8_t __attribute__((ext_vector_type(8)));
typedef float    f32x4_t __attribute__((ext_vector_type(4)));

#define HD 512          // h
#define CD 256          // c
#define ND 512          // N (codebook)
#define MROWS (4*24*2048)
#define BM 32           // 32 rows/WG -> LDS ~34KB -> 4 WGs/CU (wave cap)
#define NTHR 512
#define TINV 10.0f      // 1/TEMP

// Fragment layout for MFMA B operands (validated R6): element (n,h) ->
// ((((n>>4)*16+(h>>5))*4+((h>>3)&3))*16+(n&15))*8+(h&7)
__device__ __forceinline__ int fragoff(int n, int h) {
  return ((((n >> 4) * 16 + (h >> 5)) * 4 + ((h >> 3) & 3)) * 16 + (n & 15)) * 8 + (h & 7);
}

// ---------------- prep: M = Wp @ Wq -> fp16 fragments; sb[n] = dot(Wp[n], bq)
__global__ void prep_M(const float* __restrict__ Wp, const float* __restrict__ Wq,
                       const float* __restrict__ bq, f16* __restrict__ MtF,
                       float* __restrict__ sb) {
  const int n = blockIdx.x;   // 0..511
  const int t = threadIdx.x;  // 0..255
  __shared__ float wpr[CD];
  __shared__ float sred[CD];
  wpr[t] = Wp[n * CD + t];
  __syncthreads();
  float a0 = 0.f, a1 = 0.f;
  #pragma unroll 8
  for (int c = 0; c < CD; ++c) {
    const float w = wpr[c];
    a0 = fmaf(w, Wq[c * HD + t], a0);
    a1 = fmaf(w, Wq[c * HD + t + 256], a1);
  }
  MtF[fragoff(n, t)]       = (f16)a0;
  MtF[fragoff(n, t + 256)] = (f16)a1;
  sred[t] = wpr[t] * bq[t];
  __syncthreads();
  for (int s = 128; s > 0; s >>= 1) {
    if (t < s) sred[t] += sred[t + s];
    __syncthreads();
  }
  if (t == 0) sb[n] = sred[0];
}

// ---------------- prep: WpF = GEMM3 B fragments (k-dim = n, cols = c), validated R6
__global__ void prep_WpF(const float* __restrict__ Wp, f16* __restrict__ WpF) {
  const int bx   = blockIdx.x;        // cf*16 + ks, 0..255
  const int lane = threadIdx.x;       // 0..63
  const int cf = bx >> 4, ks = bx & 15;
  const int q4 = lane >> 4, l16 = lane & 15;
  f16x8_t v;
  #pragma unroll
  for (int j = 0; j < 8; ++j)
    v[j] = (f16)Wp[(ks * 32 + q4 * 8 + j) * CD + cf * 16 + l16];
  *(f16x8_t*)(WpF + ((bx * 64) + lane) * 8) = v;
}

// ---------------- fused main: R24 CHAMPION restored verbatim (332us).
// BM=32 (LDS 34KB -> 4 WGs/CU = 32-wave cap), 16x16x32 MFMA, NT H-loads,
// NT scattered Q/P stores, swizzle (row&31)<<4, 4 barriers.
// Bracketing tests (all worse): BM=48 402 / BM=64 428; allocating stores 356;
// 32x32 MFMA 448; LDS-coalesced, reordered, deferred stores; persistence;
// pipelined staging; split kernels; wave-private -- see R5-R26 history.
// Register model: (512,4) -> 128 total regs/wave = 64 arch VGPR + 64 AGPR acc.
// SWIZZLE RULE (R4): XOR the FULL byte offset (XOR-last).
__global__ __launch_bounds__(NTHR, 4)
void fused_main(const float* __restrict__ Hl, const f16* __restrict__ MtF,
                const f16* __restrict__ WpF, const float* __restrict__ sb,
                float* __restrict__ outP, float* __restrict__ outQ) {
  __shared__ __align__(16) char AQraw[BM * HD * 2];   // 32 KiB: H fp16 -> Q fp16
  __shared__ float red[BM][8];
  __shared__ float rstat[BM];

  const int tid  = threadIdx.x;
  const int lane = tid & 63;
  const int wid  = tid >> 6;         // 0..7
  const int q4   = lane >> 4;        // 0..3
  const int l16  = lane & 15;
  const long rowbase = (long)blockIdx.x * BM;

  // ---- stage H: 32 rows x 512 fp32 -> fp16 LDS (swizzled); NT loads ----
  {
    const f32x4_t* __restrict__ src = (const f32x4_t*)(Hl + rowbase * HD);
    #pragma unroll
    for (int it = 0; it < (BM * HD / 4) / NTHR; ++it) {   // 8 iters
      const int f = it * NTHR + tid;
      const f32x4_t v = __builtin_nontemporal_load(&src[f]);
      const int row = f >> 7;
      int byteoff = row * (HD * 2) + ((f & 127) << 3);
      byteoff ^= (row & 31) << 4;                    // XOR-last!
      f16x4_t h;
      h[0] = (f16)v[0]; h[1] = (f16)v[1]; h[2] = (f16)v[2]; h[3] = (f16)v[3];
      *(f16x4_t*)(AQraw + byteoff) = h;
    }
  }
  __syncthreads();                                   // barrier 1

  // ---- GEMM1: wave tile 32 rows x 64 cols; B from MtF (L2) ----
  f32x4_t acc[2][4];
  #pragma unroll
  for (int i = 0; i < 2; ++i)
    #pragma unroll
    for (int j = 0; j < 4; ++j)
      #pragma unroll
      for (int k = 0; k < 4; ++k) acc[i][j][k] = 0.f;

  {
    const char* __restrict__ mb = (const char*)MtF + (wid * 4 * 16) * 1024 + lane * 16;
    for (int ks = 0; ks < 16; ++ks) {
      f16x8_t a[2];
      #pragma unroll
      for (int mf = 0; mf < 2; ++mf) {
        const int arow = mf * 16 + l16;
        int byteoff = arow * (HD * 2) + ks * 64 + q4 * 16;
        byteoff ^= (arow & 31) << 4;                 // XOR-last!
        a[mf] = *(const f16x8_t*)(AQraw + byteoff);
      }
      #pragma unroll
      for (int nf = 0; nf < 4; ++nf) {
        const f16x8_t b = *(const f16x8_t*)(mb + (nf * 16 + ks) * 1024);
        #pragma unroll
        for (int mf = 0; mf < 2; ++mf)
          acc[mf][nf] = __builtin_amdgcn_mfma_f32_16x16x32_f16(a[mf], b, acc[mf][nf], 0, 0, 0);
      }
    }
  }

  // ---- softmax over N=512, direct exp (|logit| <~ 54 << 88) ----
  // thread rows: mf*16 + q4*4 + r; cols: wid*64 + nf*16 + l16
  float sb10[4];
  #pragma unroll
  for (int nf = 0; nf < 4; ++nf) sb10[nf] = sb[wid * 64 + nf * 16 + l16] * TINV;

  float ps[2][4];
  #pragma unroll
  for (int mf = 0; mf < 2; ++mf)
    #pragma unroll
    for (int r = 0; r < 4; ++r) ps[mf][r] = 0.f;
  #pragma unroll
  for (int mf = 0; mf < 2; ++mf)
    #pragma unroll
    for (int nf = 0; nf < 4; ++nf)
      #pragma unroll
      for (int r = 0; r < 4; ++r) {
        const float e = __expf(fmaf(acc[mf][nf][r], TINV, sb10[nf]));
        acc[mf][nf][r] = e;
        ps[mf][r] += e;
      }
  #pragma unroll
  for (int st = 8; st >= 1; st >>= 1)
    #pragma unroll
    for (int mf = 0; mf < 2; ++mf)
      #pragma unroll
      for (int r = 0; r < 4; ++r)
        ps[mf][r] += __shfl_xor(ps[mf][r], st, 64);

  if (l16 == 0) {
    #pragma unroll
    for (int mf = 0; mf < 2; ++mf)
      #pragma unroll
      for (int r = 0; r < 4; ++r)
        red[mf * 16 + q4 * 4 + r][wid] = ps[mf][r];
  }
  __syncthreads();                                   // barrier 2
  if (tid < BM) {
    const float* rr = red[tid];
    rstat[tid] = 1.0f / (rr[0] + rr[1] + rr[2] + rr[3] + rr[4] + rr[5] + rr[6] + rr[7]);
  }
  __syncthreads();                                   // barrier 3

  // ---- normalize: Q fp32 NT stores + Q fp16 into LDS (transpose) ----
  #pragma unroll
  for (int mf = 0; mf < 2; ++mf) {
    float rinv[4];
    #pragma unroll
    for (int r = 0; r < 4; ++r)
      rinv[r] = rstat[mf * 16 + q4 * 4 + r];
    #pragma unroll
    for (int nf = 0; nf < 4; ++nf)
      #pragma unroll
      for (int r = 0; r < 4; ++r) {
        const int rloc = mf * 16 + q4 * 4 + r;
        const int col  = wid * 64 + nf * 16 + l16;
        const float q = acc[mf][nf][r] * rinv[r];
        __builtin_nontemporal_store(q, &outQ[(rowbase + rloc) * ND + col]);
        int byteoff = rloc * (ND * 2) + col * 2;
        byteoff ^= (rloc & 31) << 4;                 // XOR-last!
        *(f16*)(AQraw + byteoff) = (f16)q;
      }
  }
  __syncthreads();                                   // barrier 4: Q-LDS ready

  // ---- GEMM3: wave tile 32 rows x 32 cols; A from LDS, B from WpF (L2) ----
  f32x4_t acc2[2][2];
  #pragma unroll
  for (int i = 0; i < 2; ++i)
    #pragma unroll
    for (int j = 0; j < 2; ++j)
      #pragma unroll
      for (int k = 0; k < 4; ++k) acc2[i][j][k] = 0.f;

  {
    const char* __restrict__ wb = (const char*)WpF + (wid * 2 * 16) * 1024 + lane * 16;
    for (int ks = 0; ks < 16; ++ks) {
      f16x8_t a[2];
      #pragma unroll
      for (int mf = 0; mf < 2; ++mf) {
        const int arow = mf * 16 + l16;
        int byteoff = arow * (ND * 2) + ks * 64 + q4 * 16;
        byteoff ^= (arow & 31) << 4;                 // XOR-last!
        a[mf] = *(const f16x8_t*)(AQraw + byteoff);
      }
      #pragma unroll
      for (int nf = 0; nf < 2; ++nf) {
        const f16x8_t b = *(const f16x8_t*)(wb + (nf * 16 + ks) * 1024);
        #pragma unroll
        for (int mf = 0; mf < 2; ++mf)
          acc2[mf][nf] = __builtin_amdgcn_mfma_f32_16x16x32_f16(a[mf], b, acc2[mf][nf], 0, 0, 0);
      }
    }
  }

  // ---- P fp32 NT stores from regs ----
  #pragma unroll
  for (int mf = 0; mf < 2; ++mf)
    #pragma unroll
    for (int nf = 0; nf < 2; ++nf)
      #pragma unroll
      for (int r = 0; r < 4; ++r) {
        const long row = rowbase + mf * 16 + q4 * 4 + r;
        const int  col = wid * 32 + nf * 16 + l16;
        __builtin_nontemporal_store(acc2[mf][nf][r], &outP[row * CD + col]);
      }
}

extern "C" void kernel_launch(void* const* d_in, const int* in_sizes, int n_in,
                              void* d_out, int out_size, void* d_ws, size_t ws_size,
                              hipStream_t stream) {
  const float* Hl = (const float*)d_in[0];   // (B,T,V,H)
  const float* Wp = (const float*)d_in[1];   // (N,C)
  const float* Wq = (const float*)d_in[2];   // (C,H)
  const float* bq = (const float*)d_in[3];   // (C,)

  float* outP = (float*)d_out;                         // (M, C)
  float* outQ = (float*)d_out + (long)MROWS * CD;      // (M, N)

  f16*   MtF = (f16*)d_ws;                                        // 512 KiB
  f16*   WpF = (f16*)((char*)d_ws + ND * HD * 2);                 // 256 KiB
  float* sb  = (float*)((char*)d_ws + ND * HD * 2 + CD * ND * 2); // 2 KiB

  prep_M  <<<ND, CD, 0, stream>>>(Wp, Wq, bq, MtF, sb);
  prep_WpF<<<CD, 64, 0, stream>>>(Wp, WpF);
  fused_main<<<MROWS / BM, NTHR, 0, stream>>>(Hl, MtF, WpF, sb, outP, outQ);
}